// Round 3
// baseline (1161.809 us; speedup 1.0000x reference)
//
#include <hip/hip_runtime.h>
#include <cstdint>
#include <cstddef>

// Problem constants: B=4,S=1024 -> T=4096 tokens
#define T_TOK 4096
#define DDIM 1024
#define HDIM 4096
#define NEXP 8
#define NSHARED 2

typedef unsigned short ushort_t;
typedef __attribute__((ext_vector_type(8))) short short8;   // 8 bf16 (MFMA A/B frag)
typedef __attribute__((ext_vector_type(4))) float f32x4;    // MFMA C/D frag

__device__ inline ushort_t f2bf(float f) {
  unsigned u = __float_as_uint(f);
  u += 0x7fffu + ((u >> 16) & 1u);
  return (ushort_t)(u >> 16);
}

// async global->LDS 16B/lane. LDS dest must be wave-uniform base + lane*16;
// global source may be per-lane arbitrary (gather is legal).
__device__ inline void async_copy16(const ushort_t* g, ushort_t* l) {
  __builtin_amdgcn_global_load_lds(
      (const __attribute__((address_space(1))) void*)g,
      (__attribute__((address_space(3))) void*)l, 16, 0, 0);
}

// JAX default gelu (tanh approx), overflow-safe
__device__ inline float gelu_tanh(float x) {
  float u = 0.7978845608028654f * (x + 0.044715f * x * x * x);
  float th = 1.0f - 2.0f / (__expf(2.0f * u) + 1.0f);
  return 0.5f * x * (1.0f + th);
}

// ---------------- router: top-2 of (x@Wr + br + gumbel); count per expert ---
__global__ __launch_bounds__(256) void router_kernel(
    const float* __restrict__ x, const float* __restrict__ Wr,
    const float* __restrict__ br, const float* __restrict__ gum,
    int* __restrict__ choice, int* __restrict__ cnt) {
  int lane = threadIdx.x & 63;
  int wv = blockIdx.x * 4 + (threadIdx.x >> 6);
  if (wv >= T_TOK) return;
  const float* xr = x + (long)wv * DDIM;
  float acc[NEXP] = {0.f, 0.f, 0.f, 0.f, 0.f, 0.f, 0.f, 0.f};
  for (int d = lane; d < DDIM; d += 64) {
    float xv = xr[d];
    const float* w = Wr + d * NEXP;
#pragma unroll
    for (int e = 0; e < NEXP; e++) acc[e] += xv * w[e];
  }
#pragma unroll
  for (int e = 0; e < NEXP; e++) {
    float v = acc[e];
#pragma unroll
    for (int o = 32; o > 0; o >>= 1) v += __shfl_down(v, o);
    acc[e] = v;
  }
  if (lane == 0) {
    float vals[NEXP];
#pragma unroll
    for (int e = 0; e < NEXP; e++) vals[e] = acc[e] + br[e] + gum[(long)wv * NEXP + e];
    int i1 = 0; float b1 = vals[0];
#pragma unroll
    for (int e = 1; e < NEXP; e++) if (vals[e] > b1) { b1 = vals[e]; i1 = e; }
    int i2 = -1; float b2 = -3.4e38f;
#pragma unroll
    for (int e = 0; e < NEXP; e++) if (e != i1 && vals[e] > b2) { b2 = vals[e]; i2 = e; }
    choice[wv] = i1 | (i2 << 4);
    atomicAdd(&cnt[i1], 1);
    atomicAdd(&cnt[i2], 1);
  }
}

// ---------------- prefix: 128-aligned segment base per expert --------------
__global__ void prefix_kernel(const int* __restrict__ cnt, int* __restrict__ base,
                              int* __restrict__ fill) {
  if (threadIdx.x == 0 && blockIdx.x == 0) {
    int off = 0;
    for (int e = 0; e < NEXP; e++) {
      base[e] = off;
      off += (cnt[e] + 127) & ~127;
      fill[e] = 0;
    }
  }
}

// ---------------- scatter token ids into per-expert compact lists ----------
__global__ __launch_bounds__(256) void scatter_kernel(
    const int* __restrict__ choice, const int* __restrict__ base,
    int* __restrict__ fill, int* __restrict__ idx) {
  int t = blockIdx.x * 256 + threadIdx.x;
  if (t >= T_TOK) return;
  int c = choice[t];
  int e1 = c & 15, e2 = (c >> 4) & 15;
  int p1 = atomicAdd(&fill[e1], 1);
  idx[base[e1] + p1] = t;
  int p2 = atomicAdd(&fill[e2], 1);
  idx[base[e2] + p2] = t;
}

// ---------------- cast x fp32 -> bf16 --------------------------------------
__global__ __launch_bounds__(256) void cast_x_kernel(
    const float* __restrict__ in, ushort_t* __restrict__ out, int n4) {
  int i = blockIdx.x * 256 + threadIdx.x;
  if (i >= n4) return;
  float4 v = ((const float4*)in)[i];
  ushort4 o = make_ushort4(f2bf(v.x), f2bf(v.y), f2bf(v.z), f2bf(v.w));
  ((ushort4*)out)[i] = o;
}

// ---------------- transpose+cast: fp32 [R][C] -> bf16 [C][R] ---------------
__global__ __launch_bounds__(256) void transpose_cast(
    const float* __restrict__ in, ushort_t* __restrict__ out, int R, int C) {
  __shared__ float tile[32][33];
  long zoff = (long)blockIdx.z * R * C;
  in += zoff; out += zoff;
  int c0 = blockIdx.x * 32, r0 = blockIdx.y * 32;
  int tx = threadIdx.x, ty = threadIdx.y;  // block (32,8)
#pragma unroll
  for (int k = 0; k < 4; k++)
    tile[ty + 8 * k][tx] = in[(long)(r0 + ty + 8 * k) * C + (c0 + tx)];
  __syncthreads();
#pragma unroll
  for (int k = 0; k < 4; k++)
    out[(long)(c0 + ty + 8 * k) * R + (r0 + tx)] = f2bf(tile[tx][ty + 8 * k]);
}

// ============ GEMM1 merged: z<2 shared N-half z; z>=2 routing expert z-2 ===
// C[row][col] = gelu(A[row] . W1row[col] + bias[col]) -> bf16 h
// 128x128 tile, BK=64 (two 32-slices per barrier pair = 32 MFMA/barrier-pair)
__global__ __launch_bounds__(256) void gemm1_kernel(
    const ushort_t* __restrict__ xb, const ushort_t* __restrict__ W1t,
    const float* __restrict__ bs1, const float* __restrict__ be1,
    ushort_t* __restrict__ h_sh, ushort_t* __restrict__ h_rt,
    const int* __restrict__ cnt, const int* __restrict__ base,
    const int* __restrict__ idx) {
  __shared__ ushort_t As[2 * 128 * 32];   // [slice][row][32k]
  __shared__ ushort_t Bs[2 * 128 * 32];

  int tid = threadIdx.x;
  int z = blockIdx.z;
  int row0 = blockIdx.y * 128, col0 = blockIdx.x * 128;
  bool sh = (z < NSHARED);

  int e = 0, M = T_TOK, base_e = 0;
  const ushort_t* Bp;
  const float* bias;
  if (sh) {
    Bp = W1t + (size_t)z * HDIM * DDIM;
    bias = bs1 + (size_t)z * HDIM;
  } else {
    e = z - NSHARED; M = cnt[e];
    if (row0 >= M) return;            // block-uniform exit, before any barrier
    base_e = base[e];
    Bp = W1t + (size_t)(NSHARED + e) * HDIM * DDIM;
    bias = be1 + (size_t)e * HDIM;
  }

  int tq = tid & 3, tr = tid >> 2;
  const ushort_t *aS, *aS2;
  if (sh) {
    aS = xb + (size_t)(row0 + tr) * DDIM + tq * 8;
    aS2 = aS + (size_t)64 * DDIM;
  } else {
    int s1 = row0 + tr;      if (s1 > M - 1) s1 = M - 1;
    int s2 = row0 + tr + 64; if (s2 > M - 1) s2 = M - 1;
    aS  = xb + (size_t)idx[base_e + s1] * DDIM + tq * 8;
    aS2 = xb + (size_t)idx[base_e + s2] * DDIM + tq * 8;
  }
  const ushort_t* bS = Bp + (size_t)(col0 + tr) * DDIM + tq * 8;
  const ushort_t* bS2 = bS + (size_t)64 * DDIM;
  ushort_t* aD = As + tid * 8;
  ushort_t* bD = Bs + tid * 8;

  int lane = tid & 63, wv = tid >> 6;
  int wr = wv >> 1, wc = wv & 1;
  int ln = lane & 15, quad = lane >> 4;
  f32x4 acc[4][4] = {};
  const ushort_t* aLds = As + (wr * 64 + ln) * 32 + quad * 8;
  const ushort_t* bLds = Bs + (wc * 64 + ln) * 32 + quad * 8;

  for (int k0 = 0; k0 < DDIM; k0 += 64) {
    async_copy16(aS, aD);            async_copy16(aS2, aD + 2048);
    async_copy16(aS + 32, aD + 4096); async_copy16(aS2 + 32, aD + 6144);
    async_copy16(bS, bD);            async_copy16(bS2, bD + 2048);
    async_copy16(bS + 32, bD + 4096); async_copy16(bS2 + 32, bD + 6144);
    __syncthreads();
#pragma unroll
    for (int s = 0; s < 2; s++) {
      short8 af[4], bf[4];
#pragma unroll
      for (int i = 0; i < 4; i++) {
        af[i] = *(const short8*)(aLds + s * 4096 + i * 16 * 32);
        bf[i] = *(const short8*)(bLds + s * 4096 + i * 16 * 32);
      }
#pragma unroll
      for (int i = 0; i < 4; i++)
#pragma unroll
        for (int j = 0; j < 4; j++)
          acc[i][j] = __builtin_amdgcn_mfma_f32_16x16x32_bf16(af[i], bf[j],
                                                              acc[i][j], 0, 0, 0);
    }
    __syncthreads();
    aS += 64; aS2 += 64; bS += 64; bS2 += 64;
  }

  // epilogue: C/D layout col=lane&15, row=quad*4+reg
#pragma unroll
  for (int i = 0; i < 4; i++) {
    int rowB = row0 + wr * 64 + i * 16 + quad * 4;
#pragma unroll
    for (int j = 0; j < 4; j++) {
      int col = col0 + wc * 64 + j * 16 + ln;
      float b = bias[col];
#pragma unroll
      for (int r = 0; r < 4; r++) {
        int t = rowB + r;
        float v = gelu_tanh(acc[i][j][r] + b);
        if (sh) {
          h_sh[(size_t)t * (2 * HDIM) + (size_t)z * HDIM + col] = f2bf(v);
        } else if (t < M) {
          h_rt[((size_t)base_e + t) * HDIM + col] = f2bf(v);
        }
      }
    }
  }
}

// ============ GEMM2 merged: z<2 shared K-chunk z; z>=2 routing expert z-2 ==
// out[tok] += h . W2row[col] (+bias on designated chunk), atomicAdd fp32
__global__ __launch_bounds__(256) void gemm2_kernel(
    const ushort_t* __restrict__ h_sh, const ushort_t* __restrict__ h_rt,
    const ushort_t* __restrict__ W2t, const float* __restrict__ bs2,
    const float* __restrict__ be2, float* __restrict__ outF,
    const int* __restrict__ cnt, const int* __restrict__ base,
    const int* __restrict__ idx) {
  __shared__ ushort_t As[2 * 128 * 32];
  __shared__ ushort_t Bs[2 * 128 * 32];

  int tid = threadIdx.x;
  int z = blockIdx.z;
  int row0 = blockIdx.y * 128, col0 = blockIdx.x * 128;
  bool sh = (z < NSHARED);

  int e = 0, M = T_TOK, base_e = 0;
  const ushort_t* Ap;
  const ushort_t* Bp;
  long lda;
  if (sh) {
    // K-chunk z of merged K=8192 == shared expert z's H block
    Ap = h_sh + (size_t)z * HDIM;    // column offset within row stride 2H
    lda = 2 * HDIM;
    Bp = W2t + (size_t)z * DDIM * HDIM;
  } else {
    e = z - NSHARED; M = cnt[e];
    if (row0 >= M) return;
    base_e = base[e];
    Ap = h_rt + (size_t)base_e * HDIM;
    lda = HDIM;
    Bp = W2t + (size_t)(NSHARED + e) * DDIM * HDIM;
  }

  int tq = tid & 3, tr = tid >> 2;
  const ushort_t* aS = Ap + (long)(row0 + tr) * lda + tq * 8;
  const ushort_t* aS2 = aS + 64L * lda;
  const ushort_t* bS = Bp + (size_t)(col0 + tr) * HDIM + tq * 8;
  const ushort_t* bS2 = bS + (size_t)64 * HDIM;
  ushort_t* aD = As + tid * 8;
  ushort_t* bD = Bs + tid * 8;

  int lane = tid & 63, wv = tid >> 6;
  int wr = wv >> 1, wc = wv & 1;
  int ln = lane & 15, quad = lane >> 4;
  f32x4 acc[4][4] = {};
  const ushort_t* aLds = As + (wr * 64 + ln) * 32 + quad * 8;
  const ushort_t* bLds = Bs + (wc * 64 + ln) * 32 + quad * 8;

  for (int k0 = 0; k0 < HDIM; k0 += 64) {
    async_copy16(aS, aD);            async_copy16(aS2, aD + 2048);
    async_copy16(aS + 32, aD + 4096); async_copy16(aS2 + 32, aD + 6144);
    async_copy16(bS, bD);            async_copy16(bS2, bD + 2048);
    async_copy16(bS + 32, bD + 4096); async_copy16(bS2 + 32, bD + 6144);
    __syncthreads();
#pragma unroll
    for (int s = 0; s < 2; s++) {
      short8 af[4], bf[4];
#pragma unroll
      for (int i = 0; i < 4; i++) {
        af[i] = *(const short8*)(aLds + s * 4096 + i * 16 * 32);
        bf[i] = *(const short8*)(bLds + s * 4096 + i * 16 * 32);
      }
#pragma unroll
      for (int i = 0; i < 4; i++)
#pragma unroll
        for (int j = 0; j < 4; j++)
          acc[i][j] = __builtin_amdgcn_mfma_f32_16x16x32_bf16(af[i], bf[j],
                                                              acc[i][j], 0, 0, 0);
    }
    __syncthreads();
    aS += 64; aS2 += 64; bS += 64; bS2 += 64;
  }

#pragma unroll
  for (int i = 0; i < 4; i++) {
    int rowB = row0 + wr * 64 + i * 16 + quad * 4;
#pragma unroll
    for (int j = 0; j < 4; j++) {
      int col = col0 + wc * 64 + j * 16 + ln;
      float b;
      if (sh)
        b = (z == 0) ? (bs2[col] + bs2[DDIM + col]) : 0.0f;  // both shared biases once
      else
        b = be2[(size_t)e * DDIM + col];
#pragma unroll
      for (int r = 0; r < 4; r++) {
        int t = rowB + r;
        float v = acc[i][j][r] + b;
        if (sh) {
          atomicAdd(outF + (size_t)t * DDIM + col, v);
        } else if (t < M) {
          int tok = idx[base_e + t];
          atomicAdd(outF + (size_t)tok * DDIM + col, v);
        }
      }
    }
  }
}

extern "C" void kernel_launch(void* const* d_in, const int* in_sizes, int n_in,
                              void* d_out, int out_size, void* d_ws,
                              size_t ws_size, hipStream_t stream) {
  const float* x   = (const float*)d_in[0];
  const float* Ws1 = (const float*)d_in[1];
  const float* bs1 = (const float*)d_in[2];
  const float* Ws2 = (const float*)d_in[3];
  const float* bs2 = (const float*)d_in[4];
  const float* We1 = (const float*)d_in[5];
  const float* be1 = (const float*)d_in[6];
  const float* We2 = (const float*)d_in[7];
  const float* be2 = (const float*)d_in[8];
  const float* Wr  = (const float*)d_in[9];
  const float* br  = (const float*)d_in[10];
  const float* gum = (const float*)d_in[11];
  float* out = (float*)d_out;

  // ---- workspace layout (~320 MB) ----
  char* ws = (char*)d_ws;
  size_t off = 0;
  int* cnt    = (int*)(ws + off); off += 256;
  int* base   = (int*)(ws + off); off += 256;
  int* fill   = (int*)(ws + off); off += 256;
  int* choice = (int*)(ws + off); off += T_TOK * 4;
  int* idx    = (int*)(ws + off); off += 9216 * 4;
  off = (off + 255) & ~(size_t)255;
  ushort_t* xb   = (ushort_t*)(ws + off); off += (size_t)T_TOK * DDIM * 2;       // 8 MB
  ushort_t* W1t  = (ushort_t*)(ws + off); off += (size_t)10 * HDIM * DDIM * 2;   // 80 MB
  ushort_t* W2t  = (ushort_t*)(ws + off); off += (size_t)10 * DDIM * HDIM * 2;   // 80 MB
  ushort_t* h_sh = (ushort_t*)(ws + off); off += (size_t)T_TOK * 2 * HDIM * 2;   // 64 MB
  ushort_t* h_rt = (ushort_t*)(ws + off); off += (size_t)9216 * HDIM * 2;        // 75.5 MB
  (void)ws_size;

  hipMemsetAsync(out, 0, (size_t)T_TOK * DDIM * sizeof(float), stream);
  hipMemsetAsync(cnt, 0, 256, stream);

  router_kernel<<<T_TOK / 4, 256, 0, stream>>>(x, Wr, br, gum, choice, cnt);
  prefix_kernel<<<1, 64, 0, stream>>>(cnt, base, fill);
  scatter_kernel<<<T_TOK / 256, 256, 0, stream>>>(choice, base, fill, idx);
  cast_x_kernel<<<(T_TOK * DDIM / 4 + 255) / 256, 256, 0, stream>>>(
      x, xb, T_TOK * DDIM / 4);

  // W1: [D][H] -> bf16 [H][D]; shared experts first, then routing experts
  transpose_cast<<<dim3(HDIM / 32, DDIM / 32, NSHARED), dim3(32, 8), 0, stream>>>(
      Ws1, W1t, DDIM, HDIM);
  transpose_cast<<<dim3(HDIM / 32, DDIM / 32, NEXP), dim3(32, 8), 0, stream>>>(
      We1, W1t + (size_t)NSHARED * HDIM * DDIM, DDIM, HDIM);
  // W2: [H][D] -> bf16 [D][H]
  transpose_cast<<<dim3(DDIM / 32, HDIM / 32, NSHARED), dim3(32, 8), 0, stream>>>(
      Ws2, W2t, HDIM, DDIM);
  transpose_cast<<<dim3(DDIM / 32, HDIM / 32, NEXP), dim3(32, 8), 0, stream>>>(
      We2, W2t + (size_t)NSHARED * DDIM * HDIM, HDIM, DDIM);

  // merged GEMM1: all 10 expert-passes in one dispatch (K=1024)
  gemm1_kernel<<<dim3(HDIM / 128, T_TOK / 128, NSHARED + NEXP), 256, 0, stream>>>(
      xb, W1t, bs1, be1, h_sh, h_rt, cnt, base, idx);
  // merged GEMM2: shared as 2 K-chunks + 8 routing experts (K=4096 each)
  gemm2_kernel<<<dim3(DDIM / 128, T_TOK / 128, NSHARED + NEXP), 256, 0, stream>>>(
      h_sh, h_rt, W2t, bs2, be2, out, cnt, base, idx);

  (void)in_sizes; (void)n_in; (void)out_size;
}

// Round 4
// 1039.707 us; speedup vs baseline: 1.1174x; 1.1174x over previous
//
#include <hip/hip_runtime.h>
#include <cstdint>
#include <cstddef>

// Problem constants: B=4,S=1024 -> T=4096 tokens
#define T_TOK 4096
#define DDIM 1024
#define HDIM 4096
#define NEXP 8
#define NSHARED 2
#define RT_CAP 9216   // max compact routing rows (8192 + 8*128 align slack)

typedef unsigned short ushort_t;
typedef __attribute__((ext_vector_type(8))) short short8;   // 8 bf16 (MFMA A/B frag)
typedef __attribute__((ext_vector_type(4))) float f32x4;    // MFMA C/D frag

__device__ inline ushort_t f2bf(float f) {
  unsigned u = __float_as_uint(f);
  u += 0x7fffu + ((u >> 16) & 1u);
  return (ushort_t)(u >> 16);
}

// async global->LDS 16B/lane. LDS dest must be wave-uniform base + lane*16;
// global source may be per-lane arbitrary (gather is legal).
__device__ inline void async_copy16(const ushort_t* g, ushort_t* l) {
  __builtin_amdgcn_global_load_lds(
      (const __attribute__((address_space(1))) void*)g,
      (__attribute__((address_space(3))) void*)l, 16, 0, 0);
}

// JAX default gelu (tanh approx), overflow-safe
__device__ inline float gelu_tanh(float x) {
  float u = 0.7978845608028654f * (x + 0.044715f * x * x * x);
  float th = 1.0f - 2.0f / (__expf(2.0f * u) + 1.0f);
  return 0.5f * x * (1.0f + th);
}

// XCD-affine swizzle: within a z-slice (Gx*Gy blocks, Gy=32, Gx in {8,32}),
// remap flat id so id%8 == x-panel%8. Dispatch assigns XCD ~ linear%8, so each
// XCD keeps ONE 128-col B panel hot in its private 4MB L2.
__device__ inline void swizzle_xy(int* bx, int* by) {
  int l = blockIdx.x + gridDim.x * blockIdx.y;  // within-slice linear
  int g = l >> 8;                               // octet group (Gx>8 case)
  *bx = (l & 7) + (g << 3);
  *by = (l >> 3) & 31;
}

// ---------------- router: top-2 of (x@Wr + br + gumbel); count per expert ---
__global__ __launch_bounds__(256) void router_kernel(
    const float* __restrict__ x, const float* __restrict__ Wr,
    const float* __restrict__ br, const float* __restrict__ gum,
    int* __restrict__ choice, int* __restrict__ cnt) {
  int lane = threadIdx.x & 63;
  int wv = blockIdx.x * 4 + (threadIdx.x >> 6);
  if (wv >= T_TOK) return;
  const float* xr = x + (long)wv * DDIM;
  float acc[NEXP] = {0.f, 0.f, 0.f, 0.f, 0.f, 0.f, 0.f, 0.f};
  for (int d = lane; d < DDIM; d += 64) {
    float xv = xr[d];
    const float* w = Wr + d * NEXP;
#pragma unroll
    for (int e = 0; e < NEXP; e++) acc[e] += xv * w[e];
  }
#pragma unroll
  for (int e = 0; e < NEXP; e++) {
    float v = acc[e];
#pragma unroll
    for (int o = 32; o > 0; o >>= 1) v += __shfl_down(v, o);
    acc[e] = v;
  }
  if (lane == 0) {
    float vals[NEXP];
#pragma unroll
    for (int e = 0; e < NEXP; e++) vals[e] = acc[e] + br[e] + gum[(long)wv * NEXP + e];
    int i1 = 0; float b1 = vals[0];
#pragma unroll
    for (int e = 1; e < NEXP; e++) if (vals[e] > b1) { b1 = vals[e]; i1 = e; }
    int i2 = -1; float b2 = -3.4e38f;
#pragma unroll
    for (int e = 0; e < NEXP; e++) if (e != i1 && vals[e] > b2) { b2 = vals[e]; i2 = e; }
    choice[wv] = i1 | (i2 << 4);
    atomicAdd(&cnt[i1], 1);
    atomicAdd(&cnt[i2], 1);
  }
}

// ---------------- prefix: 128-aligned segment base per expert --------------
__global__ void prefix_kernel(const int* __restrict__ cnt, int* __restrict__ base,
                              int* __restrict__ fill) {
  if (threadIdx.x == 0 && blockIdx.x == 0) {
    int off = 0;
    for (int e = 0; e < NEXP; e++) {
      base[e] = off;
      off += (cnt[e] + 127) & ~127;
      fill[e] = 0;
    }
  }
}

// -------- scatter token ids into per-expert lists; record inverse pos ------
__global__ __launch_bounds__(256) void scatter_kernel(
    const int* __restrict__ choice, const int* __restrict__ base,
    int* __restrict__ fill, int* __restrict__ idx, int* __restrict__ pos) {
  int t = blockIdx.x * 256 + threadIdx.x;
  if (t >= T_TOK) return;
  int c = choice[t];
  int e1 = c & 15, e2 = (c >> 4) & 15;
  int p1 = base[e1] + atomicAdd(&fill[e1], 1);
  idx[p1] = t; pos[2 * t] = p1;
  int p2 = base[e2] + atomicAdd(&fill[e2], 1);
  idx[p2] = t; pos[2 * t + 1] = p2;
}

// ---------------- cast x fp32 -> bf16 --------------------------------------
__global__ __launch_bounds__(256) void cast_x_kernel(
    const float* __restrict__ in, ushort_t* __restrict__ out, int n4) {
  int i = blockIdx.x * 256 + threadIdx.x;
  if (i >= n4) return;
  float4 v = ((const float4*)in)[i];
  ushort4 o = make_ushort4(f2bf(v.x), f2bf(v.y), f2bf(v.z), f2bf(v.w));
  ((ushort4*)out)[i] = o;
}

// ------- transpose+cast all 10 experts: fp32 [R][C] -> bf16 [C][R] ---------
// z<2 reads inS (shared), else inE (routing); out slice z.
__global__ __launch_bounds__(256) void transpose_cast10(
    const float* __restrict__ inS, const float* __restrict__ inE,
    ushort_t* __restrict__ out, int R, int C) {
  __shared__ float tile[32][33];
  int z = blockIdx.z;
  const float* in = (z < NSHARED) ? inS + (size_t)z * R * C
                                  : inE + (size_t)(z - NSHARED) * R * C;
  ushort_t* op = out + (size_t)z * R * C;
  int c0 = blockIdx.x * 32, r0 = blockIdx.y * 32;
  int tx = threadIdx.x, ty = threadIdx.y;  // block (32,8)
#pragma unroll
  for (int k = 0; k < 4; k++)
    tile[ty + 8 * k][tx] = in[(long)(r0 + ty + 8 * k) * C + (c0 + tx)];
  __syncthreads();
#pragma unroll
  for (int k = 0; k < 4; k++)
    op[(long)(c0 + ty + 8 * k) * R + (r0 + tx)] = f2bf(tile[tx][ty + 8 * k]);
}

// ============ GEMM1 merged: z<2 shared N-half z; z>=2 routing expert z-2 ===
// 128x128 tile, BK=64; h = bf16(gelu(A.W1^T + bias))
__global__ __launch_bounds__(256) void gemm1_kernel(
    const ushort_t* __restrict__ xb, const ushort_t* __restrict__ W1t,
    const float* __restrict__ bs1, const float* __restrict__ be1,
    ushort_t* __restrict__ h_sh, ushort_t* __restrict__ h_rt,
    const int* __restrict__ cnt, const int* __restrict__ base,
    const int* __restrict__ idx) {
  __shared__ ushort_t As[2 * 128 * 32];
  __shared__ ushort_t Bs[2 * 128 * 32];

  int tid = threadIdx.x;
  int z = blockIdx.z;
  int bx, by; swizzle_xy(&bx, &by);
  int row0 = by * 128, col0 = bx * 128;
  bool sh = (z < NSHARED);

  int e = 0, M = T_TOK, base_e = 0;
  const ushort_t* Bp;
  const float* bias;
  if (sh) {
    Bp = W1t + (size_t)z * HDIM * DDIM;
    bias = bs1 + (size_t)z * HDIM;
  } else {
    e = z - NSHARED; M = cnt[e];
    if (row0 >= M) return;            // block-uniform exit, before any barrier
    base_e = base[e];
    Bp = W1t + (size_t)(NSHARED + e) * HDIM * DDIM;
    bias = be1 + (size_t)e * HDIM;
  }

  int tq = tid & 3, tr = tid >> 2;
  const ushort_t *aS, *aS2;
  if (sh) {
    aS = xb + (size_t)(row0 + tr) * DDIM + tq * 8;
    aS2 = aS + (size_t)64 * DDIM;
  } else {
    int s1 = row0 + tr;      if (s1 > M - 1) s1 = M - 1;
    int s2 = row0 + tr + 64; if (s2 > M - 1) s2 = M - 1;
    aS  = xb + (size_t)idx[base_e + s1] * DDIM + tq * 8;
    aS2 = xb + (size_t)idx[base_e + s2] * DDIM + tq * 8;
  }
  const ushort_t* bS = Bp + (size_t)(col0 + tr) * DDIM + tq * 8;
  const ushort_t* bS2 = bS + (size_t)64 * DDIM;
  ushort_t* aD = As + tid * 8;
  ushort_t* bD = Bs + tid * 8;

  int lane = tid & 63, wv = tid >> 6;
  int wr = wv >> 1, wc = wv & 1;
  int ln = lane & 15, quad = lane >> 4;
  f32x4 acc[4][4] = {};
  const ushort_t* aLds = As + (wr * 64 + ln) * 32 + quad * 8;
  const ushort_t* bLds = Bs + (wc * 64 + ln) * 32 + quad * 8;

  for (int k0 = 0; k0 < DDIM; k0 += 64) {
    async_copy16(aS, aD);             async_copy16(aS2, aD + 2048);
    async_copy16(aS + 32, aD + 4096); async_copy16(aS2 + 32, aD + 6144);
    async_copy16(bS, bD);             async_copy16(bS2, bD + 2048);
    async_copy16(bS + 32, bD + 4096); async_copy16(bS2 + 32, bD + 6144);
    __syncthreads();
#pragma unroll
    for (int s = 0; s < 2; s++) {
      short8 af[4], bf[4];
#pragma unroll
      for (int i = 0; i < 4; i++) {
        af[i] = *(const short8*)(aLds + s * 4096 + i * 16 * 32);
        bf[i] = *(const short8*)(bLds + s * 4096 + i * 16 * 32);
      }
#pragma unroll
      for (int i = 0; i < 4; i++)
#pragma unroll
        for (int j = 0; j < 4; j++)
          acc[i][j] = __builtin_amdgcn_mfma_f32_16x16x32_bf16(af[i], bf[j],
                                                              acc[i][j], 0, 0, 0);
    }
    __syncthreads();
    aS += 64; aS2 += 64; bS += 64; bS2 += 64;
  }

  // epilogue: C/D layout col=lane&15, row=quad*4+reg
#pragma unroll
  for (int i = 0; i < 4; i++) {
    int rowB = row0 + wr * 64 + i * 16 + quad * 4;
#pragma unroll
    for (int j = 0; j < 4; j++) {
      int col = col0 + wc * 64 + j * 16 + ln;
      float b = bias[col];
#pragma unroll
      for (int r = 0; r < 4; r++) {
        int t = rowB + r;
        float v = gelu_tanh(acc[i][j][r] + b);
        if (sh) {
          h_sh[(size_t)t * (2 * HDIM) + (size_t)z * HDIM + col] = f2bf(v);
        } else if (t < M) {
          h_rt[((size_t)base_e + t) * HDIM + col] = f2bf(v);
        }
      }
    }
  }
}

// ============ GEMM2: atomic-free. z=0/1: shared expert z -> out_shA/B ======
// z>=2: routing expert z-2 -> compact out_rt rows. Plain fp32 stores.
__global__ __launch_bounds__(256) void gemm2_kernel(
    const ushort_t* __restrict__ h_sh, const ushort_t* __restrict__ h_rt,
    const ushort_t* __restrict__ W2t, float* __restrict__ outShA,
    float* __restrict__ outShB, float* __restrict__ outRt,
    const int* __restrict__ cnt, const int* __restrict__ base) {
  __shared__ ushort_t As[2 * 128 * 32];
  __shared__ ushort_t Bs[2 * 128 * 32];

  int tid = threadIdx.x;
  int z = blockIdx.z;
  int bx, by; swizzle_xy(&bx, &by);
  int row0 = by * 128, col0 = bx * 128;
  bool sh = (z < NSHARED);

  int e = 0, M = T_TOK, base_e = 0;
  const ushort_t* Ap;
  long lda;
  const ushort_t* Bp;
  float* outP;
  if (sh) {
    Ap = h_sh + (size_t)z * HDIM;   // column offset within row stride 2H
    lda = 2 * HDIM;
    Bp = W2t + (size_t)z * DDIM * HDIM;
    outP = (z == 0) ? outShA : outShB;
  } else {
    e = z - NSHARED; M = cnt[e];
    if (row0 >= M) return;
    base_e = base[e];
    Ap = h_rt + (size_t)base_e * HDIM;
    lda = HDIM;
    Bp = W2t + (size_t)(NSHARED + e) * DDIM * HDIM;
    outP = outRt + (size_t)base_e * DDIM;
  }

  int tq = tid & 3, tr = tid >> 2;
  const ushort_t* aS = Ap + (long)(row0 + tr) * lda + tq * 8;
  const ushort_t* aS2 = aS + 64L * lda;
  const ushort_t* bS = Bp + (size_t)(col0 + tr) * HDIM + tq * 8;
  const ushort_t* bS2 = bS + (size_t)64 * HDIM;
  ushort_t* aD = As + tid * 8;
  ushort_t* bD = Bs + tid * 8;

  int lane = tid & 63, wv = tid >> 6;
  int wr = wv >> 1, wc = wv & 1;
  int ln = lane & 15, quad = lane >> 4;
  f32x4 acc[4][4] = {};
  const ushort_t* aLds = As + (wr * 64 + ln) * 32 + quad * 8;
  const ushort_t* bLds = Bs + (wc * 64 + ln) * 32 + quad * 8;

  for (int k0 = 0; k0 < HDIM; k0 += 64) {
    async_copy16(aS, aD);             async_copy16(aS2, aD + 2048);
    async_copy16(aS + 32, aD + 4096); async_copy16(aS2 + 32, aD + 6144);
    async_copy16(bS, bD);             async_copy16(bS2, bD + 2048);
    async_copy16(bS + 32, bD + 4096); async_copy16(bS2 + 32, bD + 6144);
    __syncthreads();
#pragma unroll
    for (int s = 0; s < 2; s++) {
      short8 af[4], bf[4];
#pragma unroll
      for (int i = 0; i < 4; i++) {
        af[i] = *(const short8*)(aLds + s * 4096 + i * 16 * 32);
        bf[i] = *(const short8*)(bLds + s * 4096 + i * 16 * 32);
      }
#pragma unroll
      for (int i = 0; i < 4; i++)
#pragma unroll
        for (int j = 0; j < 4; j++)
          acc[i][j] = __builtin_amdgcn_mfma_f32_16x16x32_bf16(af[i], bf[j],
                                                              acc[i][j], 0, 0, 0);
    }
    __syncthreads();
    aS += 64; aS2 += 64; bS += 64; bS2 += 64;
  }

#pragma unroll
  for (int i = 0; i < 4; i++) {
    int rowB = row0 + wr * 64 + i * 16 + quad * 4;
#pragma unroll
    for (int j = 0; j < 4; j++) {
      int col = col0 + wc * 64 + j * 16 + ln;
#pragma unroll
      for (int r = 0; r < 4; r++) {
        int t = rowB + r;
        if (sh || t < M) outP[(size_t)t * DDIM + col] = acc[i][j][r];
      }
    }
  }
}

// ---- combine: out = shA + shB + rt[p1] + rt[p2] + (bs2 sum + be2[e1]+be2[e2])
__global__ __launch_bounds__(256) void combine_kernel(
    const float* __restrict__ shA, const float* __restrict__ shB,
    const float* __restrict__ rt, const float* __restrict__ bs2,
    const float* __restrict__ be2, const int* __restrict__ choice,
    const int* __restrict__ pos, float* __restrict__ out) {
  int i = blockIdx.x * 256 + threadIdx.x;     // over T*D/4
  int t = i >> 8;                             // D/4 = 256
  int d4 = i & 255;
  int c = choice[t];
  int e1 = c & 15, e2 = (c >> 4) & 15;
  long p1 = (long)pos[2 * t] * 256 + d4;
  long p2 = (long)pos[2 * t + 1] * 256 + d4;
  float4 a = ((const float4*)shA)[i];
  float4 b = ((const float4*)shB)[i];
  float4 r1 = ((const float4*)rt)[p1];
  float4 r2 = ((const float4*)rt)[p2];
  float4 b0 = ((const float4*)bs2)[d4];
  float4 b1 = ((const float4*)bs2)[256 + d4];
  float4 c1 = ((const float4*)be2)[e1 * 256 + d4];
  float4 c2 = ((const float4*)be2)[e2 * 256 + d4];
  float4 o;
  o.x = a.x + b.x + r1.x + r2.x + b0.x + b1.x + c1.x + c2.x;
  o.y = a.y + b.y + r1.y + r2.y + b0.y + b1.y + c1.y + c2.y;
  o.z = a.z + b.z + r1.z + r2.z + b0.z + b1.z + c1.z + c2.z;
  o.w = a.w + b.w + r1.w + r2.w + b0.w + b1.w + c1.w + c2.w;
  ((float4*)out)[i] = o;
}

extern "C" void kernel_launch(void* const* d_in, const int* in_sizes, int n_in,
                              void* d_out, int out_size, void* d_ws,
                              size_t ws_size, hipStream_t stream) {
  const float* x   = (const float*)d_in[0];
  const float* Ws1 = (const float*)d_in[1];
  const float* bs1 = (const float*)d_in[2];
  const float* Ws2 = (const float*)d_in[3];
  const float* bs2 = (const float*)d_in[4];
  const float* We1 = (const float*)d_in[5];
  const float* be1 = (const float*)d_in[6];
  const float* We2 = (const float*)d_in[7];
  const float* be2 = (const float*)d_in[8];
  const float* Wr  = (const float*)d_in[9];
  const float* br  = (const float*)d_in[10];
  const float* gum = (const float*)d_in[11];
  float* out = (float*)d_out;

  // ---- workspace layout (~308 MB) ----
  char* ws = (char*)d_ws;
  size_t off = 0;
  int* cnt    = (int*)(ws + off); off += 256;
  int* base   = (int*)(ws + off); off += 256;
  int* fill   = (int*)(ws + off); off += 256;
  int* choice = (int*)(ws + off); off += T_TOK * 4;
  int* idx    = (int*)(ws + off); off += RT_CAP * 4;
  int* pos    = (int*)(ws + off); off += T_TOK * 8;
  off = (off + 255) & ~(size_t)255;
  ushort_t* xb   = (ushort_t*)(ws + off); off += (size_t)T_TOK * DDIM * 2;       // 8 MB
  ushort_t* W1t  = (ushort_t*)(ws + off); off += (size_t)10 * HDIM * DDIM * 2;   // 80 MB
  ushort_t* W2t  = (ushort_t*)(ws + off); off += (size_t)10 * DDIM * HDIM * 2;   // 80 MB
  ushort_t* h_sh = (ushort_t*)(ws + off); off += (size_t)T_TOK * 2 * HDIM * 2;   // 64 MB
  ushort_t* h_rt = (ushort_t*)(ws + off); off += (size_t)RT_CAP * HDIM * 2;      // 75.5 MB
  // out buffers ALIAS W1t (dead after gemm1; rewritten by transposes each launch)
  float* outShA = (float*)W1t;                         // 16.8 MB
  float* outShB = outShA + (size_t)T_TOK * DDIM;       // 16.8 MB
  float* outRt  = outShB + (size_t)T_TOK * DDIM;       // 37.7 MB (71.3 <= 80)
  (void)ws_size;

  hipMemsetAsync(cnt, 0, 256, stream);
  router_kernel<<<T_TOK / 4, 256, 0, stream>>>(x, Wr, br, gum, choice, cnt);
  prefix_kernel<<<1, 64, 0, stream>>>(cnt, base, fill);
  scatter_kernel<<<T_TOK / 256, 256, 0, stream>>>(choice, base, fill, idx, pos);
  cast_x_kernel<<<(T_TOK * DDIM / 4 + 255) / 256, 256, 0, stream>>>(
      x, xb, T_TOK * DDIM / 4);

  // W1: [D][H] -> bf16 [H][D] (10 experts, one dispatch); W2 likewise
  transpose_cast10<<<dim3(HDIM / 32, DDIM / 32, 10), dim3(32, 8), 0, stream>>>(
      Ws1, We1, W1t, DDIM, HDIM);
  transpose_cast10<<<dim3(DDIM / 32, HDIM / 32, 10), dim3(32, 8), 0, stream>>>(
      Ws2, We2, W2t, HDIM, DDIM);

  // merged GEMM1: all 10 expert-passes (K=1024)
  gemm1_kernel<<<dim3(HDIM / 128, T_TOK / 128, NSHARED + NEXP), 256, 0, stream>>>(
      xb, W1t, bs1, be1, h_sh, h_rt, cnt, base, idx);
  // GEMM2: z=0/1 shared experts -> outShA/B; z>=2 routing -> outRt (K=4096)
  gemm2_kernel<<<dim3(DDIM / 128, T_TOK / 128, NSHARED + NEXP), 256, 0, stream>>>(
      h_sh, h_rt, W2t, outShA, outShB, outRt, cnt, base);
  // final gather-add (+ all output biases)
  combine_kernel<<<T_TOK * DDIM / 4 / 256, 256, 0, stream>>>(
      outShA, outShB, outRt, bs2, be2, choice, pos, out);

  (void)in_sizes; (void)n_in; (void)out_size;
}